// Round 9
// baseline (137.743 us; speedup 1.0000x reference)
//
#include <hip/hip_runtime.h>
#include <math.h>

#define DIM 64
#define KC 32
#define NPTS 32768
#define LOG_2PI 1.8378770664093453f
#define C0 (-58.0f)   // fixed logsumexp reference: logp <= -58.81 always (logdet>=0, logw<=0)
#define ST 66         // prep LDS row stride (words): even -> 8B-aligned float2 rows

typedef __attribute__((ext_vector_type(8))) short short8;
typedef __attribute__((ext_vector_type(4))) float float4v;

__device__ __forceinline__ unsigned short f2bf(float f) {
    unsigned u = __float_as_uint(f);
    u += 0x7FFFu + ((u >> 16) & 1u);   // RNE
    return (unsigned short)(u >> 16);
}

__device__ __forceinline__ float rdlane(float v, int l) {
    return __int_as_float(__builtin_amdgcn_readlane(__float_as_int(v), l));
}

// DPP adds (VALU pipe, not LDS) — HW-verified correct in rounds 7/8.
template <int CTRL>
__device__ __forceinline__ float dpp_add(float x) {
    int t = __builtin_amdgcn_mov_dpp(__float_as_int(x), CTRL, 0xF, 0xF, true);
    return x + __int_as_float(t);
}
__device__ __forceinline__ float sum16(float x) {   // sum within each 16-lane row
    x = dpp_add<0xB1>(x);    // quad_perm [1,0,3,2]  : xor 1
    x = dpp_add<0x4E>(x);    // quad_perm [2,3,0,1]  : xor 2
    x = dpp_add<0x141>(x);   // row_half_mirror      : xor 4
    x = dpp_add<0x140>(x);   // row_mirror           : xor 8
    return x;
}

// ============================================================================
// Prep: FROZEN from round 8 (control; 46.5 us). Two-wave split Cholesky +
// inverse, static full-row bounds backed by zero tails. See r8 notes.
// ============================================================================
__global__ __launch_bounds__(256) void prep_kernel(
    const float* __restrict__ L, const float* __restrict__ mu,
    const float* __restrict__ w, short* __restrict__ Bpack,
    float* __restrict__ cstC)
{
    const int k = blockIdx.x;
    const int t = threadIdx.x;
    const int wv = t >> 6;
    const int ln = t & 63;
    __shared__ float Llds[DIM * ST];
    __shared__ float Sig[DIM * ST];
    __shared__ float Clds[DIM * ST];
    __shared__ float Ylds[DIM * ST];   // Ylds[j*ST + i] = M[i][j]
    __shared__ float qlds[DIM];
    __shared__ float rdbuf[DIM];
    __shared__ float ldet;

    for (int idx = t; idx < DIM * DIM; idx += 256) {
        int r = idx >> 6, c = idx & 63;
        float v = L[(size_t)k * DIM * DIM + idx];
        Llds[r * ST + c] = (c <= r) ? v : 0.f;
    }
    for (int idx = t; idx < DIM * ST; idx += 256) {
        Clds[idx] = 0.f;
        Ylds[idx] = 0.f;
    }
    __syncthreads();

    {
        float Lr[DIM];
        const float2* lp = (const float2*)(Llds + ln * ST);
#pragma unroll
        for (int p = 0; p < 32; ++p) {
            float2 v = lp[p];
            Lr[2 * p] = v.x; Lr[2 * p + 1] = v.y;
        }
#pragma unroll 1
        for (int jj = 0; jj < 16; ++jj) {
            const int j = wv * 16 + jj;
            const float2* up = (const float2*)(Llds + j * ST);
            float a0 = 0.f, a1 = 0.f, a2 = 0.f, a3 = 0.f;
#pragma unroll
            for (int p = 0; p < 32; p += 2) {
                float2 u0 = up[p], u1 = up[p + 1];
                a0 = fmaf(Lr[2 * p], u0.x, a0);
                a1 = fmaf(Lr[2 * p + 1], u0.y, a1);
                a2 = fmaf(Lr[2 * p + 2], u1.x, a2);
                a3 = fmaf(Lr[2 * p + 3], u1.y, a3);
            }
            float s = (a0 + a1) + (a2 + a3);
            if (j == ln) s += 1.f;
            Sig[ln * ST + j] = s;
        }
    }
    __syncthreads();

    {
        const float2* crow = (const float2*)(Clds + ln * ST);
        const float2* yrow = (const float2*)(Ylds + ln * ST);
        float ld2 = 0.f;
#pragma unroll 1
        for (int c = 0; c < DIM; ++c) {
            const float2* urow = (const float2*)(Clds + c * ST);
            float sinv = 0.f;
            if (wv == 0) {
                float sc0 = 0.f, sc1 = 0.f;
#pragma unroll
                for (int p = 0; p < 32; ++p) {
                    float2 cu = urow[p], cr = crow[p];
                    sc0 = fmaf(cr.x, cu.x, sc0);
                    sc1 = fmaf(cr.y, cu.y, sc1);
                }
                float schol = Sig[ln * ST + c] - (sc0 + sc1);
                float d2 = rdlane(schol, c);
                ld2 += __logf(d2);
                float rd = __builtin_amdgcn_rsqf(d2);
                Clds[ln * ST + c] = schol * rd;
                if (ln == 0) rdbuf[c] = rd;
            } else if (wv == 1) {
                float si0 = 0.f, si1 = 0.f;
#pragma unroll
                for (int p = 0; p < 32; ++p) {
                    float2 cu = urow[p], yr = yrow[p];
                    si0 = fmaf(yr.x, cu.x, si0);
                    si1 = fmaf(yr.y, cu.y, si1);
                }
                sinv = ((ln == c) ? 1.f : 0.f) - (si0 + si1);
            }
            __syncthreads();
            if (wv == 1) {
                float yv = sinv * rdbuf[c];
                Ylds[ln * ST + c] = (ln <= c) ? yv : 0.f;
            }
        }
        if (wv == 0 && ln == 0) ldet = ld2;
    }
    __syncthreads();

    if (wv == 0) {
        const float* muk = mu + k * DIM;
        float qv = 0.f;
#pragma unroll 8
        for (int j = 0; j < DIM; ++j)
            qv = fmaf(Ylds[j * ST + ln], muk[j], qv);
        qlds[ln] = qv;
        if (ln == 0) {
            float wm = -3.0e38f;
            for (int i = 0; i < KC; ++i) wm = fmaxf(wm, w[i]);
            float se = 0.f;
            for (int i = 0; i < KC; ++i) se += __expf(w[i] - wm);
            float logw = w[k] - (wm + __logf(se));
            cstC[k] = -0.5f * (DIM * LOG_2PI + ldet) + logw - C0;
        }
    }
    __syncthreads();

    {
        const int ct = wv;
        const int col = ct * 16 + (ln & 15);
        const int kb = (ln >> 4) * 8;
#pragma unroll
        for (int kt = 0; kt < 3; ++kt) {
            short8 v;
            if (kt < 2) {
#pragma unroll
                for (int e = 0; e < 8; ++e)
                    v[e] = (short)f2bf(Ylds[(kt * 32 + kb + e) * ST + col]);
            } else {
#pragma unroll
                for (int e = 0; e < 8; ++e)
                    v[e] = (short)((kb + e == 0) ? f2bf(-qlds[col]) : 0);
            }
            *(short8*)(Bpack + ((size_t)(k * 12 + ct * 3 + kt) * 64 + ln) * 8) = v;
        }
    }
}

// ============================================================================
// Main v3: r3's measured-best skeleton (direct-global B, no LDS staging, no
// staging barrier, (256,4) occupancy) + 2 row-tiles per wave (halves L2
// fragment traffic: each 48 KB of B-fragment reads now feeds 32 rows) + DPP
// reductions (VALU pipe). 2048 blocks x 256 thr = 8192 waves; wave = 32 rows
// x 4 components. Fixed-reference logsumexp -> plain sums.
// ============================================================================
__global__ __launch_bounds__(256, 4) void main_kernel(
    const float* __restrict__ X, const short* __restrict__ Bpack,
    const float* __restrict__ cstC, float* __restrict__ partials)
{
    const int tid = threadIdx.x;
    const int lane = tid & 63;
    const int wv = tid >> 6;
    const int w = blockIdx.x * 4 + wv;     // 0..8191
    const int rt = w >> 3;                 // 32-row group 0..1023
    const int ks = w & 7;                  // k in [4ks, 4ks+4)
    const int m = lane & 15;
    const int jb4 = (lane >> 4) * 2;       // float4 index of this lane's K-chunk

    // A fragments: 2 row-tiles x 2 K-halves (float4 loads)
    short8 a[2][2];
#pragma unroll
    for (int tt = 0; tt < 2; ++tt) {
        const float4* Xr = (const float4*)(X + (size_t)(rt * 32 + tt * 16 + m) * DIM);
        float4 v0 = Xr[jb4], v1 = Xr[jb4 + 1];
        float4 v2 = Xr[8 + jb4], v3 = Xr[8 + jb4 + 1];
        a[tt][0][0] = (short)f2bf(v0.x); a[tt][0][1] = (short)f2bf(v0.y);
        a[tt][0][2] = (short)f2bf(v0.z); a[tt][0][3] = (short)f2bf(v0.w);
        a[tt][0][4] = (short)f2bf(v1.x); a[tt][0][5] = (short)f2bf(v1.y);
        a[tt][0][6] = (short)f2bf(v1.z); a[tt][0][7] = (short)f2bf(v1.w);
        a[tt][1][0] = (short)f2bf(v2.x); a[tt][1][1] = (short)f2bf(v2.y);
        a[tt][1][2] = (short)f2bf(v2.z); a[tt][1][3] = (short)f2bf(v2.w);
        a[tt][1][4] = (short)f2bf(v3.x); a[tt][1][5] = (short)f2bf(v3.y);
        a[tt][1][6] = (short)f2bf(v3.z); a[tt][1][7] = (short)f2bf(v3.w);
    }
    short8 a2 = (short8)0;                 // augmented tile: x_ext[64] = 1.0
    if (lane < 16) a2[0] = (short)0x3F80;

    const short8* Bg = (const short8*)Bpack + (size_t)ks * 4 * 12 * 64;
    float acc = 0.f;
#pragma unroll
    for (int kk = 0; kk < 4; ++kk) {
        float p00 = 0.f, p01 = 0.f, p02 = 0.f, p03 = 0.f;
        float p10 = 0.f, p11 = 0.f, p12 = 0.f, p13 = 0.f;
#pragma unroll
        for (int ct = 0; ct < 4; ++ct) {
            short8 f0 = Bg[(kk * 12 + ct * 3 + 0) * 64 + lane];
            short8 f1 = Bg[(kk * 12 + ct * 3 + 1) * 64 + lane];
            short8 f2 = Bg[(kk * 12 + ct * 3 + 2) * 64 + lane];
            float4v c0 = {0.f, 0.f, 0.f, 0.f};
            c0 = __builtin_amdgcn_mfma_f32_16x16x32_bf16(a[0][0], f0, c0, 0, 0, 0);
            c0 = __builtin_amdgcn_mfma_f32_16x16x32_bf16(a[0][1], f1, c0, 0, 0, 0);
            c0 = __builtin_amdgcn_mfma_f32_16x16x32_bf16(a2, f2, c0, 0, 0, 0);
            float4v c1 = {0.f, 0.f, 0.f, 0.f};
            c1 = __builtin_amdgcn_mfma_f32_16x16x32_bf16(a[1][0], f0, c1, 0, 0, 0);
            c1 = __builtin_amdgcn_mfma_f32_16x16x32_bf16(a[1][1], f1, c1, 0, 0, 0);
            c1 = __builtin_amdgcn_mfma_f32_16x16x32_bf16(a2, f2, c1, 0, 0, 0);
            p00 = fmaf(c0[0], c0[0], p00); p01 = fmaf(c0[1], c0[1], p01);
            p02 = fmaf(c0[2], c0[2], p02); p03 = fmaf(c0[3], c0[3], p03);
            p10 = fmaf(c1[0], c1[0], p10); p11 = fmaf(c1[1], c1[1], p11);
            p12 = fmaf(c1[2], c1[2], p12); p13 = fmaf(c1[3], c1[3], p13);
        }
        const float cc = cstC[ks * 4 + kk];   // wave-uniform s_load
        acc += __expf(fmaf(-0.5f, sum16(p00), cc)) + __expf(fmaf(-0.5f, sum16(p01), cc));
        acc += __expf(fmaf(-0.5f, sum16(p02), cc)) + __expf(fmaf(-0.5f, sum16(p03), cc));
        acc += __expf(fmaf(-0.5f, sum16(p10), cc)) + __expf(fmaf(-0.5f, sum16(p11), cc));
        acc += __expf(fmaf(-0.5f, sum16(p12), cc)) + __expf(fmaf(-0.5f, sum16(p13), cc));
    }
    // the 4 lane-groups hold disjoint rows (in-group duplicates after sum16)
    acc += __shfl_xor(acc, 16, 64);
    acc += __shfl_xor(acc, 32, 64);

    __shared__ float pm[4];
    if (lane == 0) pm[wv] = acc;
    __syncthreads();
    if (tid == 0)
        partials[blockIdx.x] = (pm[0] + pm[1]) + (pm[2] + pm[3]);
}

// ============================================================================
// Final: sum 2048 partials -> out = -(C0 + log(S))
// ============================================================================
__global__ __launch_bounds__(256) void final_kernel(
    const float* __restrict__ partials, int n, float* __restrict__ out)
{
    const int tid = threadIdx.x;
    float s = 0.f;
    for (int i = tid; i < n; i += 256) s += partials[i];
#pragma unroll
    for (int m = 1; m <= 32; m <<= 1) s += __shfl_xor(s, m, 64);
    __shared__ float pm[4];
    if ((tid & 63) == 0) pm[tid >> 6] = s;
    __syncthreads();
    if (tid == 0) out[0] = -(C0 + logf((pm[0] + pm[1]) + (pm[2] + pm[3])));
}

extern "C" void kernel_launch(void* const* d_in, const int* in_sizes, int n_in,
                              void* d_out, int out_size, void* d_ws, size_t ws_size,
                              hipStream_t stream) {
    const float* X  = (const float*)d_in[0];   // [32768,64]
    const float* mu = (const float*)d_in[1];   // [32,64]
    const float* L  = (const float*)d_in[2];   // [32,64,64]
    const float* w  = (const float*)d_in[3];   // [32]
    // d_in[4] = it (unused)

    char* ws = (char*)d_ws;
    short* Bpack = (short*)ws;                         // 32*12*64*8 bf16 = 384 KB
    float* cstC  = (float*)(ws + 32 * 12 * 64 * 8 * 2);
    float* parts = cstC + KC;                          // 2048 floats

    prep_kernel<<<KC, 256, 0, stream>>>(L, mu, w, Bpack, cstC);
    main_kernel<<<2048, 256, 0, stream>>>(X, Bpack, cstC, parts);
    final_kernel<<<1, 256, 0, stream>>>(parts, 2048, (float*)d_out);
}

// Round 10
// 112.747 us; speedup vs baseline: 1.2217x; 1.2217x over previous
//
#include <hip/hip_runtime.h>
#include <math.h>

#define DIM 64
#define KC 32
#define NPTS 32768
#define LOG_2PI 1.8378770664093453f
#define C0 (-58.0f)   // fixed logsumexp reference: logp <= -58.81 always (logdet>=0, logw<=0)
#define ST 68         // prep LDS row stride (words): mult of 4 -> 16B-aligned float4 rows/cols

typedef __attribute__((ext_vector_type(8))) short short8;
typedef __attribute__((ext_vector_type(4))) float float4v;

__device__ __forceinline__ unsigned short f2bf(float f) {
    unsigned u = __float_as_uint(f);
    u += 0x7FFFu + ((u >> 16) & 1u);   // RNE
    return (unsigned short)(u >> 16);
}

__device__ __forceinline__ float rdlane(float v, int l) {
    return __int_as_float(__builtin_amdgcn_readlane(__float_as_int(v), l));
}

// DPP adds (VALU pipe, not LDS) — HW-verified correct in rounds 7/8.
template <int CTRL>
__device__ __forceinline__ float dpp_add(float x) {
    int t = __builtin_amdgcn_mov_dpp(__float_as_int(x), CTRL, 0xF, 0xF, true);
    return x + __int_as_float(t);
}
__device__ __forceinline__ float sum16(float x) {   // sum within each 16-lane row
    x = dpp_add<0xB1>(x);    // quad_perm [1,0,3,2]  : xor 1
    x = dpp_add<0x4E>(x);    // quad_perm [2,3,0,1]  : xor 2
    x = dpp_add<0x141>(x);   // row_half_mirror      : xor 4
    x = dpp_add<0x140>(x);   // row_mirror           : xor 8
    return x;
}

// ============================================================================
// Prep: one block (256 thr = 4 waves) per component k. 4-COLUMN BLOCKED
// right-looking Cholesky + inverse: 16 steps instead of 64 (r6==r8 showed
// time ~ step count, not read/barrier count). Per step: wave0 reads crow +
// 4 uniform urows, 4 dots, register 4x4 micro-factor via readlane cross-fixes,
// ds_write_b128 of 4 columns + rdbuf; wave1 concurrently does 4 inverse dots,
// post-barrier sequential 4-row fix using the 6 freshly written C elements.
// Invariants (generalize r8): at step c rows c..c+3 have exact zeros at cols
// >= c (junk lands only at future steps); all intra-step race terms multiply
// Y-zeros; register fixes restore exactly the missed l in [c, c+j) terms.
// Bpack[k]: 12 B-fragments: elem e of lane ln = B[kt*32+(ln>>4)*8+e][ct*16+(ln&15)],
//   B[j][i] = M[i][j] (j<64), augmented row 64 = -q. cstC[k] = cst_k - C0.
// ============================================================================
__global__ __launch_bounds__(256) void prep_kernel(
    const float* __restrict__ L, const float* __restrict__ mu,
    const float* __restrict__ w, short* __restrict__ Bpack,
    float* __restrict__ cstC)
{
    const int k = blockIdx.x;
    const int t = threadIdx.x;
    const int wv = t >> 6;
    const int ln = t & 63;
    __shared__ float Llds[DIM * ST];
    __shared__ float Sig[DIM * ST];
    __shared__ float Clds[DIM * ST];
    __shared__ float Ylds[DIM * ST];   // Ylds[a*ST + b] = M[b][a]
    __shared__ float qlds[DIM];
    __shared__ float rdbuf[DIM];
    __shared__ float ldet;

    // ---- P0: load tril(L); zero C and Y (zero tails back static bounds)
    for (int idx = t; idx < DIM * DIM; idx += 256) {
        int r = idx >> 6, c = idx & 63;
        float v = L[(size_t)k * DIM * DIM + idx];
        Llds[r * ST + c] = (c <= r) ? v : 0.f;
    }
    for (int idx = t; idx < DIM * ST; idx += 256) {
        Clds[idx] = 0.f;
        Ylds[idx] = 0.f;
    }
    __syncthreads();

    // ---- P1: Sigma[ln][j], 16 cols per wave (tril zeros -> full sums exact)
    {
        float Lr[DIM];
        const float2* lp = (const float2*)(Llds + ln * ST);
#pragma unroll
        for (int p = 0; p < 32; ++p) {
            float2 v = lp[p];
            Lr[2 * p] = v.x; Lr[2 * p + 1] = v.y;
        }
#pragma unroll 1
        for (int jj = 0; jj < 16; ++jj) {
            const int j = wv * 16 + jj;
            const float2* up = (const float2*)(Llds + j * ST);
            float a0 = 0.f, a1 = 0.f, a2 = 0.f, a3 = 0.f;
#pragma unroll
            for (int p = 0; p < 32; p += 2) {
                float2 u0 = up[p], u1 = up[p + 1];
                a0 = fmaf(Lr[2 * p], u0.x, a0);
                a1 = fmaf(Lr[2 * p + 1], u0.y, a1);
                a2 = fmaf(Lr[2 * p + 2], u1.x, a2);
                a3 = fmaf(Lr[2 * p + 3], u1.y, a3);
            }
            float s = (a0 + a1) + (a2 + a3);
            if (j == ln) s += 1.f;
            Sig[ln * ST + j] = s;
        }
    }
    __syncthreads();

    // ---- P2: 4-col blocked Cholesky + inverse, two waves, 16 steps
    {
        const float2* crow = (const float2*)(Clds + ln * ST);   // C row ln (w0)
        const float2* yrow = (const float2*)(Ylds + ln * ST);   // M column ln (w1)
        float ld2 = 0.f;   // logdet accumulator (wave 0, uniform)
#pragma unroll 1
        for (int c = 0; c < DIM; c += 4) {
            const float2* u0 = (const float2*)(Clds + (c + 0) * ST);
            const float2* u1 = (const float2*)(Clds + (c + 1) * ST);
            const float2* u2 = (const float2*)(Clds + (c + 2) * ST);
            const float2* u3 = (const float2*)(Clds + (c + 3) * ST);
            float si0 = 0.f, si1 = 0.f, si2 = 0.f, si3 = 0.f;
            if (wv == 0) {
                float d0a = 0.f, d0b = 0.f, d1a = 0.f, d1b = 0.f;
                float d2a = 0.f, d2b = 0.f, d3a = 0.f, d3b = 0.f;
#pragma unroll
                for (int p = 0; p < 32; ++p) {
                    float2 cr = crow[p];
                    float2 a0 = u0[p], a1 = u1[p], a2 = u2[p], a3 = u3[p];
                    d0a = fmaf(cr.x, a0.x, d0a); d0b = fmaf(cr.y, a0.y, d0b);
                    d1a = fmaf(cr.x, a1.x, d1a); d1b = fmaf(cr.y, a1.y, d1b);
                    d2a = fmaf(cr.x, a2.x, d2a); d2b = fmaf(cr.y, a2.y, d2b);
                    d3a = fmaf(cr.x, a3.x, d3a); d3b = fmaf(cr.y, a3.y, d3b);
                }
                const float4 sg = *(const float4*)(Sig + ln * ST + c);
                float s0 = sg.x - (d0a + d0b);
                float s1 = sg.y - (d1a + d1b);
                float s2 = sg.z - (d2a + d2b);
                float s3 = sg.w - (d3a + d3b);
                // 4x4 micro-factorization (registers + readlane)
                float dd0 = rdlane(s0, c + 0);
                float rd0 = __builtin_amdgcn_rsqf(dd0);
                float c0v = s0 * rd0;
                s1 = fmaf(-c0v, rdlane(c0v, c + 1), s1);
                s2 = fmaf(-c0v, rdlane(c0v, c + 2), s2);
                s3 = fmaf(-c0v, rdlane(c0v, c + 3), s3);
                float dd1 = rdlane(s1, c + 1);
                float rd1 = __builtin_amdgcn_rsqf(dd1);
                float c1v = s1 * rd1;
                s2 = fmaf(-c1v, rdlane(c1v, c + 2), s2);
                s3 = fmaf(-c1v, rdlane(c1v, c + 3), s3);
                float dd2 = rdlane(s2, c + 2);
                float rd2 = __builtin_amdgcn_rsqf(dd2);
                float c2v = s2 * rd2;
                s3 = fmaf(-c2v, rdlane(c2v, c + 3), s3);
                float dd3 = rdlane(s3, c + 3);
                float rd3 = __builtin_amdgcn_rsqf(dd3);
                float c3v = s3 * rd3;
                ld2 += (__logf(dd0) + __logf(dd1)) + (__logf(dd2) + __logf(dd3));
                *(float4*)(Clds + ln * ST + c) = make_float4(c0v, c1v, c2v, c3v);
                if (ln == 0) *(float4*)(rdbuf + c) = make_float4(rd0, rd1, rd2, rd3);
            } else if (wv == 1) {
                float e0a = 0.f, e0b = 0.f, e1a = 0.f, e1b = 0.f;
                float e2a = 0.f, e2b = 0.f, e3a = 0.f, e3b = 0.f;
#pragma unroll
                for (int p = 0; p < 32; ++p) {
                    float2 yr = yrow[p];
                    float2 a0 = u0[p], a1 = u1[p], a2 = u2[p], a3 = u3[p];
                    e0a = fmaf(yr.x, a0.x, e0a); e0b = fmaf(yr.y, a0.y, e0b);
                    e1a = fmaf(yr.x, a1.x, e1a); e1b = fmaf(yr.y, a1.y, e1b);
                    e2a = fmaf(yr.x, a2.x, e2a); e2b = fmaf(yr.y, a2.y, e2b);
                    e3a = fmaf(yr.x, a3.x, e3a); e3b = fmaf(yr.y, a3.y, e3b);
                }
                si0 = ((ln == c + 0) ? 1.f : 0.f) - (e0a + e0b);
                si1 = ((ln == c + 1) ? 1.f : 0.f) - (e1a + e1b);
                si2 = ((ln == c + 2) ? 1.f : 0.f) - (e2a + e2b);
                si3 = ((ln == c + 3) ? 1.f : 0.f) - (e3a + e3b);
            }
            __syncthreads();   // publishes C cols c..c+3 + rdbuf[c..c+3]
            if (wv == 1) {
                const float4 rdv = *(const float4*)(rdbuf + c);
                float C10 = Clds[(c + 1) * ST + c];
                float C20 = Clds[(c + 2) * ST + c];
                float C21 = Clds[(c + 2) * ST + c + 1];
                float C30 = Clds[(c + 3) * ST + c];
                float C31 = Clds[(c + 3) * ST + c + 1];
                float C32 = Clds[(c + 3) * ST + c + 2];
                float y0 = si0 * rdv.x;
                float y1 = (si1 - C10 * y0) * rdv.y;
                float y2 = (si2 - C20 * y0 - C21 * y1) * rdv.z;
                float y3 = (si3 - C30 * y0 - C31 * y1 - C32 * y2) * rdv.w;
                float4 yo;
                yo.x = (ln <= c + 0) ? y0 : 0.f;   // exact zeros above diag of M
                yo.y = (ln <= c + 1) ? y1 : 0.f;
                yo.z = (ln <= c + 2) ? y2 : 0.f;
                yo.w = (ln <= c + 3) ? y3 : 0.f;
                *(float4*)(Ylds + ln * ST + c) = yo;   // M rows c..c+3, col ln
            }
        }
        if (wv == 0 && ln == 0) ldet = ld2;
    }
    __syncthreads();   // Y complete, ldet visible

    // ---- q + cst (wave 0)
    if (wv == 0) {
        const float* muk = mu + k * DIM;
        float qv = 0.f;
#pragma unroll 8
        for (int j = 0; j < DIM; ++j)
            qv = fmaf(Ylds[j * ST + ln], muk[j], qv);   // M[ln][j]
        qlds[ln] = qv;
        if (ln == 0) {
            float wm = -3.0e38f;
            for (int i = 0; i < KC; ++i) wm = fmaxf(wm, w[i]);
            float se = 0.f;
            for (int i = 0; i < KC; ++i) se += __expf(w[i] - wm);
            float logw = w[k] - (wm + __logf(se));
            cstC[k] = -0.5f * (DIM * LOG_2PI + ldet) + logw - C0;
        }
    }
    __syncthreads();

    // ---- P3: emission; wave = col-tile ct. B[j][col] = M[col][j] = Ylds[j*ST+col]
    {
        const int ct = wv;
        const int col = ct * 16 + (ln & 15);
        const int kb = (ln >> 4) * 8;
#pragma unroll
        for (int kt = 0; kt < 3; ++kt) {
            short8 v;
            if (kt < 2) {
#pragma unroll
                for (int e = 0; e < 8; ++e)
                    v[e] = (short)f2bf(Ylds[(kt * 32 + kb + e) * ST + col]);
            } else {
#pragma unroll
                for (int e = 0; e < 8; ++e)
                    v[e] = (short)((kb + e == 0) ? f2bf(-qlds[col]) : 0);
            }
            *(short8*)(Bpack + ((size_t)(k * 12 + ct * 3 + kt) * 64 + ln) * 8) = v;
        }
    }
}

// ============================================================================
// Main: r8 verbatim (measured best): block = k-subset (4 comps) x 128 rows;
// 2048 blocks x 256 thr; B slice (48 KB) staged once into LDS; DPP sum16.
// ============================================================================
__global__ __launch_bounds__(256, 2) void main_kernel(
    const float* __restrict__ X, const float* __restrict__ Bpack,
    const float* __restrict__ cstC, float* __restrict__ partials)
{
    const int tid = threadIdx.x;
    const int lane = tid & 63;
    const int wv = tid >> 6;
    const int ks = blockIdx.x & 7;         // k in [4ks, 4ks+4)
    const int g = blockIdx.x >> 3;         // row group: 128 rows

    __shared__ float4 Bsh[3072];           // 48 KB
    {
        const float4* Bg = (const float4*)Bpack + (size_t)ks * 3072;
#pragma unroll
        for (int it = 0; it < 12; ++it)
            Bsh[it * 256 + tid] = Bg[it * 256 + tid];
    }

    const int rbase = g * 128 + wv * 32;
    const int jb = (lane >> 4) * 8;
    const float* Xr0 = X + (size_t)(rbase + (lane & 15)) * DIM;
    const float* Xr1 = Xr0 + 16 * DIM;
    short8 a0, a1, b0r, b1r;
#pragma unroll
    for (int e = 0; e < 8; ++e) {
        a0[e] = (short)f2bf(Xr0[jb + e]);
        a1[e] = (short)f2bf(Xr0[32 + jb + e]);
        b0r[e] = (short)f2bf(Xr1[jb + e]);
        b1r[e] = (short)f2bf(Xr1[32 + jb + e]);
    }
    short8 a2 = (short8)0;                 // augmented tile: x_ext[64] = 1.0
    if (lane < 16) a2[0] = (short)0x3F80;

    __syncthreads();

    const short8* Bs = (const short8*)Bsh;
    float acc = 0.f;
#pragma unroll
    for (int kk = 0; kk < 4; ++kk) {
        const int k = ks * 4 + kk;
        float p0 = 0.f, p1 = 0.f, p2 = 0.f, p3 = 0.f;
        float r0 = 0.f, r1 = 0.f, r2 = 0.f, r3 = 0.f;
#pragma unroll
        for (int ct = 0; ct < 4; ++ct) {
            short8 f0 = Bs[(kk * 12 + ct * 3 + 0) * 64 + lane];
            short8 f1 = Bs[(kk * 12 + ct * 3 + 1) * 64 + lane];
            short8 f2 = Bs[(kk * 12 + ct * 3 + 2) * 64 + lane];
            float4v c0 = {0.f, 0.f, 0.f, 0.f};
            c0 = __builtin_amdgcn_mfma_f32_16x16x32_bf16(a0, f0, c0, 0, 0, 0);
            c0 = __builtin_amdgcn_mfma_f32_16x16x32_bf16(a1, f1, c0, 0, 0, 0);
            c0 = __builtin_amdgcn_mfma_f32_16x16x32_bf16(a2, f2, c0, 0, 0, 0);
            float4v c1 = {0.f, 0.f, 0.f, 0.f};
            c1 = __builtin_amdgcn_mfma_f32_16x16x32_bf16(b0r, f0, c1, 0, 0, 0);
            c1 = __builtin_amdgcn_mfma_f32_16x16x32_bf16(b1r, f1, c1, 0, 0, 0);
            c1 = __builtin_amdgcn_mfma_f32_16x16x32_bf16(a2, f2, c1, 0, 0, 0);
            p0 = fmaf(c0[0], c0[0], p0); p1 = fmaf(c0[1], c0[1], p1);
            p2 = fmaf(c0[2], c0[2], p2); p3 = fmaf(c0[3], c0[3], p3);
            r0 = fmaf(c1[0], c1[0], r0); r1 = fmaf(c1[1], c1[1], r1);
            r2 = fmaf(c1[2], c1[2], r2); r3 = fmaf(c1[3], c1[3], r3);
        }
        const float cc = cstC[k];          // wave-uniform s_load
        acc += __expf(fmaf(-0.5f, sum16(p0), cc)) + __expf(fmaf(-0.5f, sum16(p1), cc));
        acc += __expf(fmaf(-0.5f, sum16(p2), cc)) + __expf(fmaf(-0.5f, sum16(p3), cc));
        acc += __expf(fmaf(-0.5f, sum16(r0), cc)) + __expf(fmaf(-0.5f, sum16(r1), cc));
        acc += __expf(fmaf(-0.5f, sum16(r2), cc)) + __expf(fmaf(-0.5f, sum16(r3), cc));
    }
    // the 4 lane-groups hold disjoint rows (in-group duplicates after sum16)
    acc += __shfl_xor(acc, 16, 64);
    acc += __shfl_xor(acc, 32, 64);

    __shared__ float pm[4];
    if (lane == 0) pm[wv] = acc;
    __syncthreads();
    if (tid == 0)
        partials[blockIdx.x] = (pm[0] + pm[1]) + (pm[2] + pm[3]);
}

// ============================================================================
// Final: sum 2048 partials -> out = -(C0 + log(S))
// ============================================================================
__global__ __launch_bounds__(256) void final_kernel(
    const float* __restrict__ partials, int n, float* __restrict__ out)
{
    const int tid = threadIdx.x;
    float s = 0.f;
    for (int i = tid; i < n; i += 256) s += partials[i];
#pragma unroll
    for (int m = 1; m <= 32; m <<= 1) s += __shfl_xor(s, m, 64);
    __shared__ float pm[4];
    if ((tid & 63) == 0) pm[tid >> 6] = s;
    __syncthreads();
    if (tid == 0) out[0] = -(C0 + logf((pm[0] + pm[1]) + (pm[2] + pm[3])));
}

extern "C" void kernel_launch(void* const* d_in, const int* in_sizes, int n_in,
                              void* d_out, int out_size, void* d_ws, size_t ws_size,
                              hipStream_t stream) {
    const float* X  = (const float*)d_in[0];   // [32768,64]
    const float* mu = (const float*)d_in[1];   // [32,64]
    const float* L  = (const float*)d_in[2];   // [32,64,64]
    const float* w  = (const float*)d_in[3];   // [32]
    // d_in[4] = it (unused)

    char* ws = (char*)d_ws;
    short* Bpack = (short*)ws;                         // 32*12*64*8 bf16 = 384 KB
    float* cstC  = (float*)(ws + 32 * 12 * 64 * 8 * 2);
    float* parts = cstC + KC;                          // 2048 floats

    prep_kernel<<<KC, 256, 0, stream>>>(L, mu, w, Bpack, cstC);
    main_kernel<<<2048, 256, 0, stream>>>(X, (const float*)Bpack, cstC, parts);
    final_kernel<<<1, 256, 0, stream>>>(parts, 2048, (float*)d_out);
}